// Round 10
// baseline (227.180 us; speedup 1.0000x reference)
//
#include <hip/hip_runtime.h>
#include <math.h>

static constexpr int B_ = 4;
static constexpr int L_ = 1024;
static constexpr int S_ = 1024;
static constexpr int DMODEL = 512;
static constexpr int NH = 8;
static constexpr int DH = 64;
static constexpr int NBH = 32;   // B_*NH

typedef __attribute__((ext_vector_type(8))) short s8;      // 8 bf16 (4 VGPRs)
typedef __attribute__((ext_vector_type(4))) float floatx4; // MFMA accumulator / native f32x4

__device__ __forceinline__ short f2bf(float f) {           // RNE f32->bf16
  unsigned u = __float_as_uint(f);
  return (short)((u + 0x7fffu + ((u >> 16) & 1u)) >> 16);
}
__device__ __forceinline__ float bf2f(short s) {
  return __uint_as_float(((unsigned)(unsigned short)s) << 16);
}

// ---------------------------------------------------------------------------
// prep: blocks [0,1024): W (512x512 f32 [k][n]) -> WT bf16 [n][k].
//       blocks [1024,1152): bandS init to -1e30.
// ---------------------------------------------------------------------------
__global__ __launch_bounds__(256)
void prep_kernel(const float* __restrict__ Wq, const float* __restrict__ Wk,
                 const float* __restrict__ Wv, const float* __restrict__ Wo,
                 short* __restrict__ WT, float* __restrict__ bandS) {
  __shared__ float t[32][33];
  if (blockIdx.x < 1024) {
    const int z = blockIdx.x >> 8;
    const int rem = blockIdx.x & 255;
    const int k0 = (rem >> 4) << 5, n0 = (rem & 15) << 5;
    const float* W = (z == 0) ? Wq : (z == 1) ? Wk : (z == 2) ? Wv : Wo;
    short* dw = WT + (size_t)z * 262144;
    const int row = threadIdx.x >> 3;                    // 0..31
    const int c4 = (threadIdx.x & 7) << 2;               // 0,4,..28
    const float4 f = *(const float4*)(W + (size_t)(k0 + row) * 512 + n0 + c4);
    t[row][c4 + 0] = f.x; t[row][c4 + 1] = f.y; t[row][c4 + 2] = f.z; t[row][c4 + 3] = f.w;
    __syncthreads();
#pragma unroll
    for (int j = 0; j < 4; ++j)
      dw[(size_t)(n0 + row) * 512 + k0 + c4 + j] = f2bf(t[c4 + j][row]);
  } else {
    const int i = (blockIdx.x - 1024) * 256 + threadIdx.x;   // 0..32767
    const float4 m4 = make_float4(-1e30f, -1e30f, -1e30f, -1e30f);
    *(float4*)(bandS + ((size_t)i << 3)) = m4;
    *(float4*)(bandS + ((size_t)i << 3) + 4) = m4;
  }
}

// ---------------------------------------------------------------------------
// q/k/v projections, one launch, reading f32 inputs directly (in-reg cvt).
// z=0: q->(B,H,L,D); z=1: k->(B,H,S,D) (LDS-repacked s8 stores);
// z=2: v dual scalar store vT (B,H,D,S) + vS (B,H,S,D).
// ---------------------------------------------------------------------------
__global__ __launch_bounds__(256)
void proj_qkv_kernel(const float* __restrict__ qf, const float* __restrict__ kf,
                     const float* __restrict__ vf, const short* __restrict__ WTall,
                     short* __restrict__ qk, short* __restrict__ vT,
                     short* __restrict__ vS) {
  __shared__ short tileS[64][72];
  const int z = blockIdx.z;
  const float* A = (z == 0) ? qf : (z == 1) ? kf : vf;
  const short* WT = WTall + (size_t)z * 262144;
  const int K = DMODEL;
  const int tid = threadIdx.x;
  const int lane = tid & 63, w = tid >> 6;
  const int wm = w >> 1, wn = w & 1;
  const int m0 = blockIdx.y * 64, n0 = blockIdx.x * 64;
  const int kl = (lane >> 4) << 3;
  const float* pA = A + (size_t)(m0 + wm * 32 + (lane & 15)) * K + kl;
  const short* pB = WT + (size_t)(n0 + wn * 32 + (lane & 15)) * K + kl;
  const size_t f16K = (size_t)16 * K;
  floatx4 acc00 = {0,0,0,0}, acc01 = {0,0,0,0}, acc10 = {0,0,0,0}, acc11 = {0,0,0,0};
  for (int k = 0; k < K; k += 32) {
    const float4 fa0 = *(const float4*)(pA + k);
    const float4 fa1 = *(const float4*)(pA + k + 4);
    const float4 fb0 = *(const float4*)(pA + f16K + k);
    const float4 fb1 = *(const float4*)(pA + f16K + k + 4);
    s8 a0, a1;
    a0[0] = f2bf(fa0.x); a0[1] = f2bf(fa0.y); a0[2] = f2bf(fa0.z); a0[3] = f2bf(fa0.w);
    a0[4] = f2bf(fa1.x); a0[5] = f2bf(fa1.y); a0[6] = f2bf(fa1.z); a0[7] = f2bf(fa1.w);
    a1[0] = f2bf(fb0.x); a1[1] = f2bf(fb0.y); a1[2] = f2bf(fb0.z); a1[3] = f2bf(fb0.w);
    a1[4] = f2bf(fb1.x); a1[5] = f2bf(fb1.y); a1[6] = f2bf(fb1.z); a1[7] = f2bf(fb1.w);
    const s8 b0 = *(const s8*)(pB + k);
    const s8 b1 = *(const s8*)(pB + f16K + k);
    acc00 = __builtin_amdgcn_mfma_f32_16x16x32_bf16(a0, b0, acc00, 0, 0, 0);
    acc01 = __builtin_amdgcn_mfma_f32_16x16x32_bf16(a0, b1, acc01, 0, 0, 0);
    acc10 = __builtin_amdgcn_mfma_f32_16x16x32_bf16(a1, b0, acc10, 0, 0, 0);
    acc11 = __builtin_amdgcn_mfma_f32_16x16x32_bf16(a1, b1, acc11, 0, 0, 0);
  }
  const int crow = (lane >> 4) << 2;
  const int ccol = lane & 15;
  if (z < 2) {
#pragma unroll
    for (int fm = 0; fm < 2; ++fm)
#pragma unroll
      for (int fn = 0; fn < 2; ++fn) {
        const floatx4 acc = (fm == 0) ? ((fn == 0) ? acc00 : acc01)
                                      : ((fn == 0) ? acc10 : acc11);
#pragma unroll
        for (int r = 0; r < 4; ++r)
          tileS[wm * 32 + fm * 16 + crow + r][wn * 32 + fn * 16 + ccol] = f2bf(acc[r]);
      }
    __syncthreads();
    const int b = m0 >> 10, l0 = m0 & 1023, h = n0 >> 6;
    short* base = qk + (size_t)z * 2097152 + ((size_t)((b * NH + h) * L_ + l0)) * DH;
#pragma unroll
    for (int qk2 = 0; qk2 < 2; ++qk2) {
      const int c = tid + qk2 * 256;
      const int row = c >> 3, off = (c & 7) << 3;
      *(s8*)(base + (size_t)row * DH + off) = *(const s8*)&tileS[row][off];
    }
  } else {
#pragma unroll
    for (int fm = 0; fm < 2; ++fm)
#pragma unroll
      for (int fn = 0; fn < 2; ++fn) {
        const floatx4 acc = (fm == 0) ? ((fn == 0) ? acc00 : acc01)
                                      : ((fn == 0) ? acc10 : acc11);
        const int col = n0 + wn * 32 + fn * 16 + ccol;
#pragma unroll
        for (int r = 0; r < 4; ++r) {
          const int row = m0 + wm * 32 + fm * 16 + crow + r;
          const int b = row >> 10, l = row & 1023, h = col >> 6, d = col & 63;
          const short val = f2bf(acc[r]);
          vT[((size_t)((b * NH + h) * DH + d)) * S_ + l] = val;
          vS[((size_t)((b * NH + h) * S_ + l)) * DH + d] = val;
        }
      }
  }
}

// ---------------------------------------------------------------------------
// Scores in bf16 via LDS repack; band (|l-s|<=3) stored f32 (pre-rounding).
// ---------------------------------------------------------------------------
__global__ __launch_bounds__(256)
void scores_bf16_kernel(const short* __restrict__ qbf, const short* __restrict__ kbf,
                        short* __restrict__ Sbf, float* __restrict__ bandS) {
  __shared__ short tileS[64][72];
  const int tid = threadIdx.x;
  const int lane = tid & 63, w = tid >> 6;
  const int wm = w >> 1, wn = w & 1;
  const int m0 = blockIdx.y * 64, n0 = blockIdx.x * 64;
  const int bh = blockIdx.z;
  const int kl = (lane >> 4) << 3;
  const short* pA = qbf + (size_t)bh * L_ * DH + (size_t)(m0 + wm * 32 + (lane & 15)) * DH + kl;
  const short* pB = kbf + (size_t)bh * S_ * DH + (size_t)(n0 + wn * 32 + (lane & 15)) * DH + kl;
  floatx4 acc00 = {0,0,0,0}, acc01 = {0,0,0,0}, acc10 = {0,0,0,0}, acc11 = {0,0,0,0};
#pragma unroll
  for (int k = 0; k < DH; k += 32) {
    const s8 a0 = *(const s8*)(pA + k);
    const s8 a1 = *(const s8*)(pA + 16 * DH + k);
    const s8 b0 = *(const s8*)(pB + k);
    const s8 b1 = *(const s8*)(pB + 16 * DH + k);
    acc00 = __builtin_amdgcn_mfma_f32_16x16x32_bf16(a0, b0, acc00, 0, 0, 0);
    acc01 = __builtin_amdgcn_mfma_f32_16x16x32_bf16(a0, b1, acc01, 0, 0, 0);
    acc10 = __builtin_amdgcn_mfma_f32_16x16x32_bf16(a1, b0, acc10, 0, 0, 0);
    acc11 = __builtin_amdgcn_mfma_f32_16x16x32_bf16(a1, b1, acc11, 0, 0, 0);
  }
  const int crow = (lane >> 4) << 2;
  const int ccol = lane & 15;
#pragma unroll
  for (int fm = 0; fm < 2; ++fm)
#pragma unroll
    for (int fn = 0; fn < 2; ++fn) {
      const floatx4 acc = (fm == 0) ? ((fn == 0) ? acc00 : acc01)
                                    : ((fn == 0) ? acc10 : acc11);
      const int col = n0 + wn * 32 + fn * 16 + ccol;
#pragma unroll
      for (int r = 0; r < 4; ++r) {
        const int row = m0 + wm * 32 + fm * 16 + crow + r;
        const float sc = acc[r] * 0.125f;
        tileS[wm * 32 + fm * 16 + crow + r][wn * 32 + fn * 16 + ccol] = f2bf(sc);
        const int dd = col - row;
        if (dd >= -3 && dd <= 3)
          bandS[(((size_t)bh << 10) + row) * 8 + dd + 3] = sc;
      }
    }
  __syncthreads();
  short* Sp = Sbf + ((size_t)bh << 20) + (size_t)m0 * S_ + n0;
#pragma unroll
  for (int q2 = 0; q2 < 2; ++q2) {
    const int c = tid + q2 * 256;
    const int row = c >> 3, off = (c & 7) << 3;
    *(s8*)(Sp + (size_t)row * S_ + off) = *(const s8*)&tileS[row][off];
  }
}

// ---------------------------------------------------------------------------
// path_mean v2: split-z (2 halves x 16 bh), staggered z-start, double-buffered
// LDS with 1-ahead register prefetch. Partial sums -> pm2[half][L][S].
// ---------------------------------------------------------------------------
__global__ __launch_bounds__(256)
void path_mean_kernel(const short* __restrict__ Sbf, float* __restrict__ pm2) {
  __shared__ float As[2 * 32 * 44];
  __shared__ float Bs[2 * 32 * 36];
  const int orig = blockIdx.x;                         // 0..2047
  const int wgid = (orig & 7) * 256 + (orig >> 3);     // bijective XCD swizzle
  const int half = wgid >> 10;
  const int tile = wgid & 1023;
  const int i0 = (tile >> 5) << 5;
  const int j0 = (tile & 31) << 5;
  const int c0 = (2 * i0 + j0) / 3;
  const int c0a = c0 & ~7;
  const int r0 = (i0 + 2 * j0) / 3;
  const int zbase = half << 4;
  const int stag = tile & 15;                          // stagger z phase
  const int tid = threadIdx.x;
  const int ti = tid >> 3;
  const int tj = tid & 7;
  const int gi = i0 + ti;
  int aoff[4], boff[4];
#pragma unroll
  for (int b = 0; b < 4; ++b) {
    const int gj = j0 + 4 * tj + b;
    const int m1 = (2 * gi + gj) / 3;
    const int m2 = (gi + 2 * gj) / 3;
    aoff[b] = ti * 44 + (m1 - c0a);
    boff[b] = (m2 - r0) * 36 + (4 * tj + b);
  }
  // staging roles: A = 32 rows x 5 s8-chunks = 160 units; B = 32 x 4 = 128
  int arow = 0, ac = 0, brow = 0, bc = 0, brow2 = 0, bc2 = 0;
  const bool isA = tid < 160;
  if (isA) { arow = tid / 5; ac = tid - arow * 5; }
  else { const int v = tid - 160; brow = v >> 2; bc = v & 3; }
  const bool hasU2 = tid < 32;
  { const int v = tid + 96; brow2 = v >> 2; bc2 = v & 3; }
  int gcA = c0a + (ac << 3); if (gcA > 1016) gcA = 1016;
  const short* pA = Sbf + (size_t)(i0 + arow) * S_ + gcA;
  const short* pB = Sbf + (size_t)(r0 + brow) * S_ + j0 + (bc << 3);
  const short* pB2 = Sbf + (size_t)(r0 + brow2) * S_ + j0 + (bc2 << 3);

  const int awr = isA ? (arow * 44 + (ac << 3)) : (brow * 36 + (bc << 3));
  const int awr2 = brow2 * 36 + (bc2 << 3);

  auto writeBuf = [&](int buf, const s8& v1, const s8& v2) {
    float4 lo, hi;
    lo.x = bf2f(v1[0]); lo.y = bf2f(v1[1]); lo.z = bf2f(v1[2]); lo.w = bf2f(v1[3]);
    hi.x = bf2f(v1[4]); hi.y = bf2f(v1[5]); hi.z = bf2f(v1[6]); hi.w = bf2f(v1[7]);
    if (isA) {
      *(float4*)&As[buf * 1408 + awr] = lo;
      *(float4*)&As[buf * 1408 + awr + 4] = hi;
    } else {
      *(float4*)&Bs[buf * 1152 + awr] = lo;
      *(float4*)&Bs[buf * 1152 + awr + 4] = hi;
    }
    if (hasU2) {
      float4 lo2, hi2;
      lo2.x = bf2f(v2[0]); lo2.y = bf2f(v2[1]); lo2.z = bf2f(v2[2]); lo2.w = bf2f(v2[3]);
      hi2.x = bf2f(v2[4]); hi2.y = bf2f(v2[5]); hi2.z = bf2f(v2[6]); hi2.w = bf2f(v2[7]);
      *(float4*)&Bs[buf * 1152 + awr2] = lo2;
      *(float4*)&Bs[buf * 1152 + awr2 + 4] = hi2;
    }
  };

  float acc[4] = {0.f, 0.f, 0.f, 0.f};
  // prologue: z index 0
  {
    const size_t zo = (size_t)(zbase + stag) << 20;
    s8 v1 = isA ? *(const s8*)(pA + zo) : *(const s8*)(pB + zo);
    s8 v2 = {};
    if (hasU2) v2 = *(const s8*)(pB2 + zo);
    writeBuf(0, v1, v2);
  }
  __syncthreads();
  for (int zz = 0; zz < 16; ++zz) {
    const int cur = zz & 1;
    s8 n1 = {}, n2 = {};
    if (zz < 15) {
      const size_t zo = (size_t)(zbase + ((zz + 1 + stag) & 15)) << 20;
      n1 = isA ? *(const s8*)(pA + zo) : *(const s8*)(pB + zo);
      if (hasU2) n2 = *(const s8*)(pB2 + zo);
    }
    const float* Ab = &As[cur * 1408];
    const float* Bb = &Bs[cur * 1152];
#pragma unroll
    for (int b = 0; b < 4; ++b)
      acc[b] = fmaf(Ab[aoff[b]], Bb[boff[b]], acc[b]);
    if (zz < 15) {
      writeBuf(1 - cur, n1, n2);
      __syncthreads();
    }
  }
  float4 o = make_float4(acc[0], acc[1], acc[2], acc[3]);
  *(float4*)&pm2[(size_t)half * (L_ * S_) + (size_t)gi * S_ + j0 + 4 * tj] = o;
}

// ---------------------------------------------------------------------------
// pm_stats: sum pm2 halves, scale 1/32; per row i (far only): pmmax, pmsum,
// E = bf16(exp(pm - max)) (0 on band).
// ---------------------------------------------------------------------------
__global__ __launch_bounds__(256)
void pm_stats_kernel(const float* __restrict__ pm2, short* __restrict__ E,
                     float* __restrict__ pmmax, float* __restrict__ pmsum) {
  const int wid = threadIdx.x >> 6, lane = threadIdx.x & 63;
  const int i = blockIdx.x * 4 + wid;
  const float* row0 = pm2 + (size_t)i * S_;
  const float* row1 = row0 + (size_t)(L_ * S_);
  const int j0 = lane << 4;
  float v[16];
#pragma unroll
  for (int c = 0; c < 4; ++c) {
    const float4 fa = *(const float4*)(row0 + j0 + c * 4);
    const float4 fb = *(const float4*)(row1 + j0 + c * 4);
    v[c * 4 + 0] = (fa.x + fb.x) * (1.f / 32.f);
    v[c * 4 + 1] = (fa.y + fb.y) * (1.f / 32.f);
    v[c * 4 + 2] = (fa.z + fb.z) * (1.f / 32.f);
    v[c * 4 + 3] = (fa.w + fb.w) * (1.f / 32.f);
  }
  float mx = -1e30f;
#pragma unroll
  for (int u = 0; u < 16; ++u) {
    const int d = i - (j0 + u);
    const bool far = (d > 3) || (d < -3);
    if (far) mx = fmaxf(mx, v[u]);
  }
#pragma unroll
  for (int off = 32; off >= 1; off >>= 1) mx = fmaxf(mx, __shfl_xor(mx, off));
  float sum = 0.f;
  short e[16];
#pragma unroll
  for (int u = 0; u < 16; ++u) {
    const int d = i - (j0 + u);
    const bool far = (d > 3) || (d < -3);
    const float ev = far ? __expf(v[u] - mx) : 0.f;
    sum += ev;
    e[u] = f2bf(ev);
  }
#pragma unroll
  for (int off = 32; off >= 1; off >>= 1) sum += __shfl_xor(sum, off);
  s8 o0, o1;
#pragma unroll
  for (int u = 0; u < 8; ++u) { o0[u] = e[u]; o1[u] = e[8 + u]; }
  short* Erow = E + (size_t)i * S_ + j0;
  *(s8*)Erow = o0;
  *(s8*)(Erow + 8) = o1;
  if (lane == 0) { pmmax[i] = mx; pmsum[i] = sum; }
}

// ---------------------------------------------------------------------------
// ev_fused: softmax-combine + E@V MFMA with inline attn write (nontemporal)
// + band epilogue; out1 stored via LDS repack.
// ---------------------------------------------------------------------------
__global__ __launch_bounds__(256)
void ev_fused_kernel(const short* __restrict__ E, const short* __restrict__ vT,
                     const short* __restrict__ vS, const float* __restrict__ bandS,
                     const float* __restrict__ pmmax, const float* __restrict__ pmsum,
                     float* __restrict__ attn, short* __restrict__ out1) {
  __shared__ float cL[64];
  __shared__ float bL[64][8];
  __shared__ short Vb[70 * 64];
  __shared__ short tileO[64][72];
  const int tid = threadIdx.x;
  const int m0 = blockIdx.x * 64;
  const int bh = blockIdx.y;
  const int b = bh >> 3, h = bh & 7;

  for (int idx = tid; idx < 560; idx += 256) {
    const int rr = idx >> 3, c8 = (idx & 7) << 3;
    int j = m0 - 3 + rr; j = j < 0 ? 0 : (j > 1023 ? 1023 : j);
    *(s8*)&Vb[rr * 64 + c8] = *(const s8*)(vS + ((size_t)bh * S_ + j) * DH + c8);
  }

  {
    const int r = tid >> 2, p = tid & 3;
    const int l = m0 + r;
    const float pmx = pmmax[l], psum = pmsum[l];
    const float* bs = bandS + (((size_t)bh << 10) + l) * 8;
    const float sa = bs[p], sb2 = bs[p + 4];          // slot 7 = -1e30 (init)
    float mx = fmaxf(sa, sb2);
    mx = fmaxf(mx, __shfl_xor(mx, 1));
    mx = fmaxf(mx, __shfl_xor(mx, 2));
    const float m = fmaxf(mx, pmx);
    const float ea = __expf(sa - m), eb = __expf(sb2 - m);
    float bsum = ea + eb;
    bsum += __shfl_xor(bsum, 1);
    bsum += __shfl_xor(bsum, 2);
    const float cpm = __expf(pmx - m);
    const float inv = 1.f / (bsum + psum * cpm);
    if (p == 0) cL[r] = cpm * inv;
    bL[r][p] = ea * inv;
    bL[r][p + 4] = eb * inv;
  }
  __syncthreads();

  const int lane = tid & 63, w = tid >> 6;
  const int wm = w >> 1, wn = w & 1;
  const int frow = lane & 15;
  const int kl = (lane >> 4) << 3;
  const int ra0 = m0 + wm * 32 + frow;
  const int lr0 = wm * 32 + frow;
  const int lr1 = lr0 + 16;
  const short* pA = E + (size_t)ra0 * S_ + kl;
  const short* pB = vT + (size_t)bh * DH * S_ + (size_t)(wn * 32 + frow) * S_ + kl;
  const float c0v = cL[lr0];
  const float c1v = cL[lr1];
  float* arow0 = attn + ((size_t)bh * L_ + ra0) * S_;
  float* arow1 = arow0 + (size_t)16 * S_;
  floatx4 acc00 = {0,0,0,0}, acc01 = {0,0,0,0}, acc10 = {0,0,0,0}, acc11 = {0,0,0,0};
  for (int k = 0; k < S_; k += 32) {
    const s8 a0 = *(const s8*)(pA + k);
    const s8 a1 = *(const s8*)(pA + 16 * S_ + k);
    const s8 b0 = *(const s8*)(pB + k);
    const s8 b1 = *(const s8*)(pB + 16 * S_ + k);
    acc00 = __builtin_amdgcn_mfma_f32_16x16x32_bf16(a0, b0, acc00, 0, 0, 0);
    acc01 = __builtin_amdgcn_mfma_f32_16x16x32_bf16(a0, b1, acc01, 0, 0, 0);
    acc10 = __builtin_amdgcn_mfma_f32_16x16x32_bf16(a1, b0, acc10, 0, 0, 0);
    acc11 = __builtin_amdgcn_mfma_f32_16x16x32_bf16(a1, b1, acc11, 0, 0, 0);
    const int jw = k + kl;
    if (wn == 0) {
      float att[8];
#pragma unroll
      for (int e = 0; e < 8; ++e) att[e] = bf2f(a0[e]) * c0v;
      const int rel = ra0 - jw;
      if ((unsigned)(rel + 3) <= 13u) {
#pragma unroll
        for (int e = 0; e < 8; ++e) {
          const int d = e - rel;
          if ((unsigned)(d + 3) <= 6u) att[e] = bL[lr0][d + 3];
        }
      }
      floatx4 v0 = {att[0], att[1], att[2], att[3]};
      floatx4 v1 = {att[4], att[5], att[6], att[7]};
      __builtin_nontemporal_store(v0, (floatx4*)(arow0 + jw));
      __builtin_nontemporal_store(v1, (floatx4*)(arow0 + jw + 4));
    } else {
      float att[8];
#pragma unroll
      for (int e = 0; e < 8; ++e) att[e] = bf2f(a1[e]) * c1v;
      const int rel = ra0 + 16 - jw;
      if ((unsigned)(rel + 3) <= 13u) {
#pragma unroll
        for (int e = 0; e < 8; ++e) {
          const int d = e - rel;
          if ((unsigned)(d + 3) <= 6u) att[e] = bL[lr1][d + 3];
        }
      }
      floatx4 v0 = {att[0], att[1], att[2], att[3]};
      floatx4 v1 = {att[4], att[5], att[6], att[7]};
      __builtin_nontemporal_store(v0, (floatx4*)(arow1 + jw));
      __builtin_nontemporal_store(v1, (floatx4*)(arow1 + jw + 4));
    }
  }

  const int crow = (lane >> 4) << 2;
  const int ccol = lane & 15;
#pragma unroll
  for (int fm = 0; fm < 2; ++fm)
#pragma unroll
    for (int r = 0; r < 4; ++r) {
      const int lrel = wm * 32 + fm * 16 + crow + r;
      const float cc = cL[lrel];
      const float4 b0v = *(const float4*)&bL[lrel][0];
      const float4 b1v = *(const float4*)&bL[lrel][4];
      const float bav[7] = {b0v.x, b0v.y, b0v.z, b0v.w, b1v.x, b1v.y, b1v.z};
#pragma unroll
      for (int fn = 0; fn < 2; ++fn) {
        const floatx4 acc = (fm == 0) ? ((fn == 0) ? acc00 : acc01)
                                      : ((fn == 0) ? acc10 : acc11);
        const int d = wn * 32 + fn * 16 + ccol;
        float corr = 0.f;
#pragma unroll
        for (int u = 0; u < 7; ++u)
          corr = fmaf(bav[u], bf2f(Vb[(lrel + u) * 64 + d]), corr);
        tileO[lrel][d] = f2bf(fmaf(cc, acc[r], corr));
      }
    }
  __syncthreads();
  short* obase = out1 + ((size_t)(b * L_ + m0)) * DMODEL + h * DH;
#pragma unroll
  for (int q2 = 0; q2 < 2; ++q2) {
    const int c = tid + q2 * 256;
    const int row = c >> 3, off = (c & 7) << 3;
    *(s8*)(obase + (size_t)row * DMODEL + off) = *(const s8*)&tileO[row][off];
  }
}

// ---------------------------------------------------------------------------
// Output projection: out(f32) = out1(bf16) @ Wo^T, float4 stores via LDS.
// ---------------------------------------------------------------------------
__global__ __launch_bounds__(256)
void proj_out_kernel(const short* __restrict__ A, const short* __restrict__ WT,
                     float* __restrict__ C) {
  __shared__ float tileF[64][68];
  const int K = DMODEL;
  const int tid = threadIdx.x;
  const int lane = tid & 63, w = tid >> 6;
  const int wm = w >> 1, wn = w & 1;
  const int m0 = blockIdx.y * 64, n0 = blockIdx.x * 64;
  const int kl = (lane >> 4) << 3;
  const short* pA = A + (size_t)(m0 + wm * 32 + (lane & 15)) * K + kl;
  const short* pB = WT + (size_t)(n0 + wn * 32 + (lane & 15)) * K + kl;
  const size_t f16K = (size_t)16 * K;
  floatx4 acc00 = {0,0,0,0}, acc01 = {0,0,0,0}, acc10 = {0,0,0,0}, acc11 = {0,0,0,0};
  for (int k = 0; k < K; k += 32) {
    const s8 a0 = *(const s8*)(pA + k);
    const s8 a1 = *(const s8*)(pA + f16K + k);
    const s8 b0 = *(const s8*)(pB + k);
    const s8 b1 = *(const s8*)(pB + f16K + k);
    acc00 = __builtin_amdgcn_mfma_f32_16x16x32_bf16(a0, b0, acc00, 0, 0, 0);
    acc01 = __builtin_amdgcn_mfma_f32_16x16x32_bf16(a0, b1, acc01, 0, 0, 0);
    acc10 = __builtin_amdgcn_mfma_f32_16x16x32_bf16(a1, b0, acc10, 0, 0, 0);
    acc11 = __builtin_amdgcn_mfma_f32_16x16x32_bf16(a1, b1, acc11, 0, 0, 0);
  }
  const int crow = (lane >> 4) << 2;
  const int ccol = lane & 15;
#pragma unroll
  for (int fm = 0; fm < 2; ++fm)
#pragma unroll
    for (int fn = 0; fn < 2; ++fn) {
      const floatx4 acc = (fm == 0) ? ((fn == 0) ? acc00 : acc01)
                                    : ((fn == 0) ? acc10 : acc11);
#pragma unroll
      for (int r = 0; r < 4; ++r)
        tileF[wm * 32 + fm * 16 + crow + r][wn * 32 + fn * 16 + ccol] = acc[r];
    }
  __syncthreads();
  float* base = C + (size_t)m0 * DMODEL + n0;
#pragma unroll
  for (int q2 = 0; q2 < 4; ++q2) {
    const int c = tid + q2 * 256;
    const int row = c >> 4, off = (c & 15) << 2;
    *(float4*)(base + (size_t)row * DMODEL + off) = *(const float4*)&tileF[row][off];
  }
}

// ---------------------------------------------------------------------------
extern "C" void kernel_launch(void* const* d_in, const int* in_sizes, int n_in,
                              void* d_out, int out_size, void* d_ws, size_t ws_size,
                              hipStream_t stream) {
  const float* queries = (const float*)d_in[0];
  const float* keys    = (const float*)d_in[1];
  const float* values  = (const float*)d_in[2];
  const float* Wq      = (const float*)d_in[3];
  const float* Wk      = (const float*)d_in[4];
  const float* Wv      = (const float*)d_in[5];
  const float* Wo      = (const float*)d_in[6];

  float* out  = (float*)d_out;                          // (B,L,512) f32
  float* attn = out + (size_t)B_ * L_ * DMODEL;         // (B,H,L,S) f32

  char* ws = (char*)d_ws;
  short* WT    = (short*)(ws);                    //  2 MiB: 4 x W^T bf16
  short* qkbf  = (short*)(ws + 2u * 1048576);     //  8 MiB: qbf + kbf
  short* vT    = (short*)(ws + 10u * 1048576);    //  4 MiB (B,H,D,S)
  short* vS    = (short*)(ws + 14u * 1048576);    //  4 MiB (B,H,S,D)
  float* pm2   = (float*)(ws + 18u * 1048576);    //  8 MiB (2,L,S) f32 partials
  short* E     = (short*)(ws + 26u * 1048576);    //  2 MiB (L,S) bf16
  float* pmmax = (float*)(ws + 28u * 1048576);    //  4 KiB
  float* pmsum = (float*)(ws + 28u * 1048576 + 4096);       // 4 KiB
  float* bandS = (float*)(ws + 29u * 1048576);    //  1 MiB (bh,l,8) f32
  short* out1  = (short*)(ws + 30u * 1048576);    //  4 MiB (B,L,512) bf16
  short* Sbf   = (short*)(ws + 34u * 1048576);    // 64 MiB (bh,L,S) bf16 -> 98 MiB

  const dim3 blk(256);

  // 0) W^T cvt + bandS init
  hipLaunchKernelGGL(prep_kernel, dim3(1152), blk, 0, stream,
                     Wq, Wk, Wv, Wo, WT, bandS);

  // 1) q/k/v projections (f32 read, in-reg cvt), one launch
  hipLaunchKernelGGL(proj_qkv_kernel, dim3(DMODEL / 64, (B_ * L_) / 64, 3),
                     blk, 0, stream, queries, keys, values, WT, qkbf, vT, vS);

  // 2) scores bf16 + exact band extraction
  hipLaunchKernelGGL(scores_bf16_kernel, dim3(S_ / 64, L_ / 64, NBH), blk, 0, stream,
                     qkbf, qkbf + 2097152, Sbf, bandS);

  // 3) path_mean split-z partials (staggered, double-buffered)
  hipLaunchKernelGGL(path_mean_kernel, dim3(2048), blk, 0, stream, Sbf, pm2);

  // 4) pm stats + E (sums the two z-halves)
  hipLaunchKernelGGL(pm_stats_kernel, dim3(L_ / 4), blk, 0, stream,
                     pm2, E, pmmax, pmsum);

  // 5) EV GEMM with fused attn write (nontemporal) + band epilogue
  hipLaunchKernelGGL(ev_fused_kernel, dim3(L_ / 64, NBH), blk, 0, stream,
                     E, vT, vS, bandS, pmmax, pmsum, attn, out1);

  // 6) out = out1 @ W_o
  hipLaunchKernelGGL(proj_out_kernel, dim3(DMODEL / 64, (B_ * L_) / 64), blk, 0, stream,
                     out1, WT + 786432, out);
}

// Round 11
// 202.513 us; speedup vs baseline: 1.1218x; 1.1218x over previous
//
#include <hip/hip_runtime.h>
#include <math.h>

static constexpr int B_ = 4;
static constexpr int L_ = 1024;
static constexpr int S_ = 1024;
static constexpr int DMODEL = 512;
static constexpr int NH = 8;
static constexpr int DH = 64;
static constexpr int NBH = 32;   // B_*NH

typedef __attribute__((ext_vector_type(8))) short s8;      // 8 bf16 (4 VGPRs)
typedef __attribute__((ext_vector_type(4))) float floatx4; // MFMA accumulator

__device__ __forceinline__ short f2bf(float f) {           // RNE f32->bf16
  unsigned u = __float_as_uint(f);
  return (short)((u + 0x7fffu + ((u >> 16) & 1u)) >> 16);
}
__device__ __forceinline__ float bf2f(short s) {
  return __uint_as_float(((unsigned)(unsigned short)s) << 16);
}

// ---------------------------------------------------------------------------
// Convert q/k/v (f32) -> contiguous bf16 segments; also init bandS to -1e30.
// ---------------------------------------------------------------------------
__global__ __launch_bounds__(256)
void cvt_inputs_kernel(const float* __restrict__ q, const float* __restrict__ k,
                       const float* __restrict__ v, short* __restrict__ dst,
                       float* __restrict__ bandS) {
  const int i = blockIdx.x * 256 + threadIdx.x;          // 0..786431
  if (i < 32768) {                                       // bandS: 32*1024*8 f32
    const float4 m4 = make_float4(-1e30f, -1e30f, -1e30f, -1e30f);
    *(float4*)(bandS + ((size_t)i << 3)) = m4;
    *(float4*)(bandS + ((size_t)i << 3) + 4) = m4;
  }
  const int arr = i >> 18;                               // 0..2 (uniform per block)
  const int off = (i & 262143) << 3;
  const float* src = (arr == 0) ? q : (arr == 1) ? k : v;
  const float4 f0 = *(const float4*)(src + off);
  const float4 f1 = *(const float4*)(src + off + 4);
  s8 o;
  o[0] = f2bf(f0.x); o[1] = f2bf(f0.y); o[2] = f2bf(f0.z); o[3] = f2bf(f0.w);
  o[4] = f2bf(f1.x); o[5] = f2bf(f1.y); o[6] = f2bf(f1.z); o[7] = f2bf(f1.w);
  *(s8*)(dst + (size_t)arr * 2097152 + off) = o;
}

// ---------------------------------------------------------------------------
// Transpose + cvt the 4 weight matrices: W (512x512 f32, [k][n]) -> WT bf16 [n][k]
// ---------------------------------------------------------------------------
__global__ __launch_bounds__(256)
void wtrans_kernel(const float* __restrict__ Wq, const float* __restrict__ Wk,
                   const float* __restrict__ Wv, const float* __restrict__ Wo,
                   short* __restrict__ WT) {
  __shared__ float t[32][33];
  const int z = blockIdx.z;
  const float* W = (z == 0) ? Wq : (z == 1) ? Wk : (z == 2) ? Wv : Wo;
  short* dst = WT + (size_t)z * 262144;
  const int k0 = blockIdx.y * 32, n0 = blockIdx.x * 32;
  const int row = threadIdx.x >> 3;          // 0..31
  const int c4 = (threadIdx.x & 7) << 2;     // 0,4,..28
  const float4 f = *(const float4*)(W + (size_t)(k0 + row) * 512 + n0 + c4);
  t[row][c4 + 0] = f.x; t[row][c4 + 1] = f.y; t[row][c4 + 2] = f.z; t[row][c4 + 3] = f.w;
  __syncthreads();
#pragma unroll
  for (int j = 0; j < 4; ++j)
    dst[(size_t)(n0 + row) * 512 + k0 + c4 + j] = f2bf(t[c4 + j][row]);
}

// ---------------------------------------------------------------------------
// q/k/v projections in one launch. z=0: q->(B,H,L,D); z=1: k->(B,H,S,D);
// z=2: v dual-store vT (B,H,D,S) + vS (B,H,S,D).
// ---------------------------------------------------------------------------
__global__ __launch_bounds__(256)
void proj_qkv_kernel(const short* __restrict__ xbf, const short* __restrict__ WTall,
                     short* __restrict__ qk, short* __restrict__ vT,
                     short* __restrict__ vS) {
  const int z = blockIdx.z;
  const short* A = xbf + (size_t)z * 2097152;
  const short* WT = WTall + (size_t)z * 262144;
  const int K = DMODEL;
  const int tid = threadIdx.x;
  const int lane = tid & 63, w = tid >> 6;
  const int wm = w >> 1, wn = w & 1;
  const int m0 = blockIdx.y * 64, n0 = blockIdx.x * 64;
  const int kl = (lane >> 4) << 3;
  const short* pA = A + (size_t)(m0 + wm * 32 + (lane & 15)) * K + kl;
  const short* pB = WT + (size_t)(n0 + wn * 32 + (lane & 15)) * K + kl;
  const size_t f16K = (size_t)16 * K;
  floatx4 acc00 = {0,0,0,0}, acc01 = {0,0,0,0}, acc10 = {0,0,0,0}, acc11 = {0,0,0,0};
  for (int k = 0; k < K; k += 32) {
    const s8 a0 = *(const s8*)(pA + k);
    const s8 a1 = *(const s8*)(pA + f16K + k);
    const s8 b0 = *(const s8*)(pB + k);
    const s8 b1 = *(const s8*)(pB + f16K + k);
    acc00 = __builtin_amdgcn_mfma_f32_16x16x32_bf16(a0, b0, acc00, 0, 0, 0);
    acc01 = __builtin_amdgcn_mfma_f32_16x16x32_bf16(a0, b1, acc01, 0, 0, 0);
    acc10 = __builtin_amdgcn_mfma_f32_16x16x32_bf16(a1, b0, acc10, 0, 0, 0);
    acc11 = __builtin_amdgcn_mfma_f32_16x16x32_bf16(a1, b1, acc11, 0, 0, 0);
  }
  const int crow = (lane >> 4) << 2;
  const int ccol = lane & 15;
#pragma unroll
  for (int fm = 0; fm < 2; ++fm)
#pragma unroll
    for (int fn = 0; fn < 2; ++fn) {
      const floatx4 acc = (fm == 0) ? ((fn == 0) ? acc00 : acc01)
                                    : ((fn == 0) ? acc10 : acc11);
      const int col = n0 + wn * 32 + fn * 16 + ccol;
#pragma unroll
      for (int r = 0; r < 4; ++r) {
        const int row = m0 + wm * 32 + fm * 16 + crow + r;
        const int b = row >> 10, l = row & 1023, h = col >> 6, d = col & 63;
        const short val = f2bf(acc[r]);
        if (z < 2) {
          qk[(size_t)z * 2097152 + ((size_t)((b * NH + h) * L_ + l)) * DH + d] = val;
        } else {
          vT[((size_t)((b * NH + h) * DH + d)) * S_ + l] = val;   // l==s here
          vS[((size_t)((b * NH + h) * S_ + l)) * DH + d] = val;
        }
      }
    }
}

// ---------------------------------------------------------------------------
// Scores in bf16: Sbf[bh][l][s] = bf16(0.125 * q.k); band (|l-s|<=3) also
// stored as f32 (pre-rounding) into bandS[bh][l][8] for exact softmax later.
// ---------------------------------------------------------------------------
__global__ __launch_bounds__(256)
void scores_bf16_kernel(const short* __restrict__ qbf, const short* __restrict__ kbf,
                        short* __restrict__ Sbf, float* __restrict__ bandS) {
  const int tid = threadIdx.x;
  const int lane = tid & 63, w = tid >> 6;
  const int wm = w >> 1, wn = w & 1;
  const int m0 = blockIdx.y * 64, n0 = blockIdx.x * 64;
  const int bh = blockIdx.z;
  const int kl = (lane >> 4) << 3;
  const short* pA = qbf + (size_t)bh * L_ * DH + (size_t)(m0 + wm * 32 + (lane & 15)) * DH + kl;
  const short* pB = kbf + (size_t)bh * S_ * DH + (size_t)(n0 + wn * 32 + (lane & 15)) * DH + kl;
  floatx4 acc00 = {0,0,0,0}, acc01 = {0,0,0,0}, acc10 = {0,0,0,0}, acc11 = {0,0,0,0};
#pragma unroll
  for (int k = 0; k < DH; k += 32) {
    const s8 a0 = *(const s8*)(pA + k);
    const s8 a1 = *(const s8*)(pA + 16 * DH + k);
    const s8 b0 = *(const s8*)(pB + k);
    const s8 b1 = *(const s8*)(pB + 16 * DH + k);
    acc00 = __builtin_amdgcn_mfma_f32_16x16x32_bf16(a0, b0, acc00, 0, 0, 0);
    acc01 = __builtin_amdgcn_mfma_f32_16x16x32_bf16(a0, b1, acc01, 0, 0, 0);
    acc10 = __builtin_amdgcn_mfma_f32_16x16x32_bf16(a1, b0, acc10, 0, 0, 0);
    acc11 = __builtin_amdgcn_mfma_f32_16x16x32_bf16(a1, b1, acc11, 0, 0, 0);
  }
  short* Sp = Sbf + ((size_t)bh << 20);
  const int crow = (lane >> 4) << 2;
  const int ccol = lane & 15;
#pragma unroll
  for (int fm = 0; fm < 2; ++fm)
#pragma unroll
    for (int fn = 0; fn < 2; ++fn) {
      const floatx4 acc = (fm == 0) ? ((fn == 0) ? acc00 : acc01)
                                    : ((fn == 0) ? acc10 : acc11);
      const int col = n0 + wn * 32 + fn * 16 + ccol;
#pragma unroll
      for (int r = 0; r < 4; ++r) {
        const int row = m0 + wm * 32 + fm * 16 + crow + r;
        const float sc = acc[r] * 0.125f;
        Sp[(size_t)row * S_ + col] = f2bf(sc);
        const int dd = col - row;
        if (dd >= -3 && dd <= 3)
          bandS[(((size_t)bh << 10) + row) * 8 + dd + 3] = sc;
      }
    }
}

// ---------------------------------------------------------------------------
// path_mean from bf16 scores (tiled gather through LDS, staged as f32).
//   pm[i][j] = (1/32) sum_bh Sc[bh][i][m1] * Sc[bh][m2][j]
// ---------------------------------------------------------------------------
__global__ __launch_bounds__(256)
void path_mean_kernel(const short* __restrict__ Sbf, float* __restrict__ pm) {
  __shared__ float As[32][44];   // rows i0.., cols c0a..c0a+39 (c0a = c0&~7)
  __shared__ float Bs[32][36];   // rows r0.., cols j0..j0+31
  const int orig = blockIdx.x;
  const int wgid = (orig & 7) * 128 + (orig >> 3);     // bijective XCD swizzle
  const int i0 = (wgid >> 5) << 5;
  const int j0 = (wgid & 31) << 5;
  const int c0 = (2 * i0 + j0) / 3;
  const int c0a = c0 & ~7;
  const int r0 = (i0 + 2 * j0) / 3;
  const int tid = threadIdx.x;
  const int ti = tid >> 3;           // 0..31 output row
  const int tj = tid & 7;            // 0..7  output col quad
  const int gi = i0 + ti;
  int aoff[4], boff[4];
#pragma unroll
  for (int b = 0; b < 4; ++b) {
    const int gj = j0 + 4 * tj + b;
    const int m1 = (2 * gi + gj) / 3;
    const int m2 = (gi + 2 * gj) / 3;
    aoff[b] = ti * 44 + (m1 - c0a);
    boff[b] = (m2 - r0) * 36 + (4 * tj + b);
  }
  const int uA = tid;
  const int uB2 = tid + 256;
  int arow = 0, ac = 0, brow = 0, bc = 0, brow2 = 0, bc2 = 0;
  bool isA = uA < 160;
  if (isA) { arow = uA / 5; ac = uA - arow * 5; }
  else { const int v = uA - 160; brow = v >> 2; bc = v & 3; }
  const bool hasU2 = tid < 32;
  { const int v = uB2 - 160; brow2 = v >> 2; bc2 = v & 3; }
  int gcA = c0a + (ac << 3); if (gcA > 1016) gcA = 1016;
  const short* pA = Sbf + (size_t)(i0 + arow) * S_ + gcA;
  const short* pB = Sbf + (size_t)(r0 + brow) * S_ + j0 + (bc << 3);
  const short* pB2 = Sbf + (size_t)(r0 + brow2) * S_ + j0 + (bc2 << 3);

  const float* As0 = &As[0][0];
  const float* Bs0 = &Bs[0][0];
  float acc[4] = {0.f, 0.f, 0.f, 0.f};
  for (int z = 0; z < NBH; ++z) {
    const size_t zo = (size_t)z << 20;
    const s8 v1 = isA ? *(const s8*)(pA + zo) : *(const s8*)(pB + zo);
    s8 v2;
    if (hasU2) v2 = *(const s8*)(pB2 + zo);
    __syncthreads();
    {
      float4 lo, hi;
      lo.x = bf2f(v1[0]); lo.y = bf2f(v1[1]); lo.z = bf2f(v1[2]); lo.w = bf2f(v1[3]);
      hi.x = bf2f(v1[4]); hi.y = bf2f(v1[5]); hi.z = bf2f(v1[6]); hi.w = bf2f(v1[7]);
      if (isA) {
        *(float4*)&As[arow][ac << 3] = lo;
        *(float4*)&As[arow][(ac << 3) + 4] = hi;
      } else {
        *(float4*)&Bs[brow][bc << 3] = lo;
        *(float4*)&Bs[brow][(bc << 3) + 4] = hi;
      }
      if (hasU2) {
        float4 lo2, hi2;
        lo2.x = bf2f(v2[0]); lo2.y = bf2f(v2[1]); lo2.z = bf2f(v2[2]); lo2.w = bf2f(v2[3]);
        hi2.x = bf2f(v2[4]); hi2.y = bf2f(v2[5]); hi2.z = bf2f(v2[6]); hi2.w = bf2f(v2[7]);
        *(float4*)&Bs[brow2][bc2 << 3] = lo2;
        *(float4*)&Bs[brow2][(bc2 << 3) + 4] = hi2;
      }
    }
    __syncthreads();
#pragma unroll
    for (int b = 0; b < 4; ++b)
      acc[b] = fmaf(As0[aoff[b]], Bs0[boff[b]], acc[b]);
  }
  float4 o = make_float4(acc[0] * (1.f / 32.f), acc[1] * (1.f / 32.f),
                         acc[2] * (1.f / 32.f), acc[3] * (1.f / 32.f));
  *(float4*)&pm[(size_t)gi * S_ + j0 + 4 * tj] = o;
}

// ---------------------------------------------------------------------------
// pm_stats: per row i (far positions only): pmmax, pmsum, E=bf16(exp(pm-max))
// ---------------------------------------------------------------------------
__global__ __launch_bounds__(256)
void pm_stats_kernel(const float* __restrict__ pm, short* __restrict__ E,
                     float* __restrict__ pmmax, float* __restrict__ pmsum) {
  const int wid = threadIdx.x >> 6, lane = threadIdx.x & 63;
  const int i = blockIdx.x * 4 + wid;
  const float* row = pm + (size_t)i * S_;
  const int j0 = lane << 4;
  float v[16];
#pragma unroll
  for (int c = 0; c < 4; ++c) {
    const float4 f = *(const float4*)(row + j0 + c * 4);
    v[c * 4 + 0] = f.x; v[c * 4 + 1] = f.y; v[c * 4 + 2] = f.z; v[c * 4 + 3] = f.w;
  }
  float mx = -1e30f;
#pragma unroll
  for (int u = 0; u < 16; ++u) {
    const int d = i - (j0 + u);
    const bool far = (d > 3) || (d < -3);
    if (far) mx = fmaxf(mx, v[u]);
  }
#pragma unroll
  for (int off = 32; off >= 1; off >>= 1) mx = fmaxf(mx, __shfl_xor(mx, off));
  float sum = 0.f;
  short e[16];
#pragma unroll
  for (int u = 0; u < 16; ++u) {
    const int d = i - (j0 + u);
    const bool far = (d > 3) || (d < -3);
    const float ev = far ? __expf(v[u] - mx) : 0.f;
    sum += ev;
    e[u] = f2bf(ev);
  }
#pragma unroll
  for (int off = 32; off >= 1; off >>= 1) sum += __shfl_xor(sum, off);
  s8 o0, o1;
#pragma unroll
  for (int u = 0; u < 8; ++u) { o0[u] = e[u]; o1[u] = e[8 + u]; }
  short* Erow = E + (size_t)i * S_ + j0;
  *(s8*)Erow = o0;
  *(s8*)(Erow + 8) = o1;
  if (lane == 0) { pmmax[i] = mx; pmsum[i] = sum; }
}

// ---------------------------------------------------------------------------
// ev_fused: per (64-row tile, bh):
//   stage 1: c[l], bandAttn[l][7] from bandS + pmmax/pmsum (exact f32 band)
//   stage 2: MFMA E@V; the A-fragments stream every E element of the tile's
//            attn rows -> write attn = c*E (band-patched) inline.
//   stage 3: out1 = c*acc + sum_band bandAttn*V (V band rows in LDS).
// ---------------------------------------------------------------------------
__global__ __launch_bounds__(256)
void ev_fused_kernel(const short* __restrict__ E, const short* __restrict__ vT,
                     const short* __restrict__ vS, const float* __restrict__ bandS,
                     const float* __restrict__ pmmax, const float* __restrict__ pmsum,
                     float* __restrict__ attn, short* __restrict__ out1) {
  __shared__ float cL[64];
  __shared__ float bL[64][8];
  __shared__ short Vb[70 * 64];
  const int tid = threadIdx.x;
  const int m0 = blockIdx.x * 64;
  const int bh = blockIdx.y;
  const int b = bh >> 3, h = bh & 7;

  // stage V band rows (m0-3 .. m0+66, clamped)
  for (int idx = tid; idx < 560; idx += 256) {
    const int rr = idx >> 3, c8 = (idx & 7) << 3;
    int j = m0 - 3 + rr; j = j < 0 ? 0 : (j > 1023 ? 1023 : j);
    *(s8*)&Vb[rr * 64 + c8] = *(const s8*)(vS + ((size_t)bh * S_ + j) * DH + c8);
  }

  // stage 1: softmax combine (4 threads per row)
  {
    const int r = tid >> 2, p = tid & 3;
    const int l = m0 + r;
    const float pmx = pmmax[l], psum = pmsum[l];
    const float* bs = bandS + (((size_t)bh << 10) + l) * 8;
    const float sa = bs[p], sb2 = bs[p + 4];          // slot 7 = -1e30 (init)
    float mx = fmaxf(sa, sb2);
    mx = fmaxf(mx, __shfl_xor(mx, 1));
    mx = fmaxf(mx, __shfl_xor(mx, 2));
    const float m = fmaxf(mx, pmx);
    const float ea = __expf(sa - m), eb = __expf(sb2 - m);
    float bsum = ea + eb;
    bsum += __shfl_xor(bsum, 1);
    bsum += __shfl_xor(bsum, 2);
    const float cpm = __expf(pmx - m);
    const float inv = 1.f / (bsum + psum * cpm);
    if (p == 0) cL[r] = cpm * inv;
    bL[r][p] = ea * inv;
    bL[r][p + 4] = eb * inv;
  }
  __syncthreads();

  const int lane = tid & 63, w = tid >> 6;
  const int wm = w >> 1, wn = w & 1;
  const int frow = lane & 15;
  const int kl = (lane >> 4) << 3;
  const int ra0 = m0 + wm * 32 + frow;               // a0 row; a1 row = ra0+16
  const int lr0 = wm * 32 + frow;                    // tile-relative rows
  const int lr1 = lr0 + 16;
  const short* pA = E + (size_t)ra0 * S_ + kl;
  const short* pB = vT + (size_t)bh * DH * S_ + (size_t)(wn * 32 + frow) * S_ + kl;
  const float c0v = cL[lr0];
  const float c1v = cL[lr1];
  float* arow0 = attn + ((size_t)bh * L_ + ra0) * S_;
  float* arow1 = arow0 + (size_t)16 * S_;
  floatx4 acc00 = {0,0,0,0}, acc01 = {0,0,0,0}, acc10 = {0,0,0,0}, acc11 = {0,0,0,0};
  for (int k = 0; k < S_; k += 32) {
    const s8 a0 = *(const s8*)(pA + k);
    const s8 a1 = *(const s8*)(pA + 16 * S_ + k);
    const s8 b0 = *(const s8*)(pB + k);
    const s8 b1 = *(const s8*)(pB + 16 * S_ + k);
    acc00 = __builtin_amdgcn_mfma_f32_16x16x32_bf16(a0, b0, acc00, 0, 0, 0);
    acc01 = __builtin_amdgcn_mfma_f32_16x16x32_bf16(a0, b1, acc01, 0, 0, 0);
    acc10 = __builtin_amdgcn_mfma_f32_16x16x32_bf16(a1, b0, acc10, 0, 0, 0);
    acc11 = __builtin_amdgcn_mfma_f32_16x16x32_bf16(a1, b1, acc11, 0, 0, 0);
    const int jw = k + kl;
    if (wn == 0) {                                   // this wave writes a0 rows
      float att[8];
#pragma unroll
      for (int e = 0; e < 8; ++e) att[e] = bf2f(a0[e]) * c0v;
      const int rel = ra0 - jw;                      // band cols: e in [rel-3, rel+3]
      if ((unsigned)(rel + 3) <= 13u) {
#pragma unroll
        for (int e = 0; e < 8; ++e) {
          const int d = e - rel;
          if ((unsigned)(d + 3) <= 6u) att[e] = bL[lr0][d + 3];
        }
      }
      *(float4*)(arow0 + jw) = make_float4(att[0], att[1], att[2], att[3]);
      *(float4*)(arow0 + jw + 4) = make_float4(att[4], att[5], att[6], att[7]);
    } else {                                         // this wave writes a1 rows
      float att[8];
#pragma unroll
      for (int e = 0; e < 8; ++e) att[e] = bf2f(a1[e]) * c1v;
      const int rel = ra0 + 16 - jw;
      if ((unsigned)(rel + 3) <= 13u) {
#pragma unroll
        for (int e = 0; e < 8; ++e) {
          const int d = e - rel;
          if ((unsigned)(d + 3) <= 6u) att[e] = bL[lr1][d + 3];
        }
      }
      *(float4*)(arow1 + jw) = make_float4(att[0], att[1], att[2], att[3]);
      *(float4*)(arow1 + jw + 4) = make_float4(att[4], att[5], att[6], att[7]);
    }
  }

  const int crow = (lane >> 4) << 2;
  const int ccol = lane & 15;
#pragma unroll
  for (int fm = 0; fm < 2; ++fm)
#pragma unroll
    for (int r = 0; r < 4; ++r) {
      const int lrel = wm * 32 + fm * 16 + crow + r;  // l - m0
      const int l = m0 + lrel;
      const float cc = cL[lrel];
      const float4 b0v = *(const float4*)&bL[lrel][0];
      const float4 b1v = *(const float4*)&bL[lrel][4];
      const float bav[7] = {b0v.x, b0v.y, b0v.z, b0v.w, b1v.x, b1v.y, b1v.z};
#pragma unroll
      for (int fn = 0; fn < 2; ++fn) {
        const floatx4 acc = (fm == 0) ? ((fn == 0) ? acc00 : acc01)
                                      : ((fn == 0) ? acc10 : acc11);
        const int d = wn * 32 + fn * 16 + ccol;
        float corr = 0.f;
#pragma unroll
        for (int u = 0; u < 7; ++u)
          corr = fmaf(bav[u], bf2f(Vb[(lrel + u) * 64 + d]), corr);
        const float val = fmaf(cc, acc[r], corr);
        out1[((size_t)(b * L_ + l)) * DMODEL + h * DH + d] = f2bf(val);
      }
    }
}

// ---------------------------------------------------------------------------
// Output projection: out(f32) = out1(bf16) @ Wo^T
// ---------------------------------------------------------------------------
__global__ __launch_bounds__(256)
void proj_out_kernel(const short* __restrict__ A, const short* __restrict__ WT,
                     float* __restrict__ C) {
  const int K = DMODEL;
  const int tid = threadIdx.x;
  const int lane = tid & 63, w = tid >> 6;
  const int wm = w >> 1, wn = w & 1;
  const int m0 = blockIdx.y * 64, n0 = blockIdx.x * 64;
  const int kl = (lane >> 4) << 3;
  const short* pA = A + (size_t)(m0 + wm * 32 + (lane & 15)) * K + kl;
  const short* pB = WT + (size_t)(n0 + wn * 32 + (lane & 15)) * K + kl;
  const size_t f16K = (size_t)16 * K;
  floatx4 acc00 = {0,0,0,0}, acc01 = {0,0,0,0}, acc10 = {0,0,0,0}, acc11 = {0,0,0,0};
  for (int k = 0; k < K; k += 32) {
    const s8 a0 = *(const s8*)(pA + k);
    const s8 a1 = *(const s8*)(pA + f16K + k);
    const s8 b0 = *(const s8*)(pB + k);
    const s8 b1 = *(const s8*)(pB + f16K + k);
    acc00 = __builtin_amdgcn_mfma_f32_16x16x32_bf16(a0, b0, acc00, 0, 0, 0);
    acc01 = __builtin_amdgcn_mfma_f32_16x16x32_bf16(a0, b1, acc01, 0, 0, 0);
    acc10 = __builtin_amdgcn_mfma_f32_16x16x32_bf16(a1, b0, acc10, 0, 0, 0);
    acc11 = __builtin_amdgcn_mfma_f32_16x16x32_bf16(a1, b1, acc11, 0, 0, 0);
  }
  const int crow = (lane >> 4) << 2;
  const int ccol = lane & 15;
#pragma unroll
  for (int fm = 0; fm < 2; ++fm)
#pragma unroll
    for (int fn = 0; fn < 2; ++fn) {
      const floatx4 acc = (fm == 0) ? ((fn == 0) ? acc00 : acc01)
                                    : ((fn == 0) ? acc10 : acc11);
      const int col = n0 + wn * 32 + fn * 16 + ccol;
#pragma unroll
      for (int r = 0; r < 4; ++r) {
        const int row = m0 + wm * 32 + fm * 16 + crow + r;
        C[(size_t)row * DMODEL + col] = acc[r];
      }
    }
}

// ---------------------------------------------------------------------------
extern "C" void kernel_launch(void* const* d_in, const int* in_sizes, int n_in,
                              void* d_out, int out_size, void* d_ws, size_t ws_size,
                              hipStream_t stream) {
  const float* queries = (const float*)d_in[0];
  const float* keys    = (const float*)d_in[1];
  const float* values  = (const float*)d_in[2];
  const float* Wq      = (const float*)d_in[3];
  const float* Wk      = (const float*)d_in[4];
  const float* Wv      = (const float*)d_in[5];
  const float* Wo      = (const float*)d_in[6];

  float* out  = (float*)d_out;                          // (B,L,512) f32
  float* attn = out + (size_t)B_ * L_ * DMODEL;         // (B,H,L,S) f32

  char* ws = (char*)d_ws;
  short* xbf   = (short*)(ws);                    // 12 MiB: q,k,v bf16
  short* WT    = (short*)(ws + 12u * 1048576);    //  2 MiB: 4 x W^T bf16
  short* qkbf  = (short*)(ws + 14u * 1048576);    //  8 MiB: qbf + kbf
  short* vT    = (short*)(ws + 22u * 1048576);    //  4 MiB (B,H,D,S)
  short* vS    = (short*)(ws + 26u * 1048576);    //  4 MiB (B,H,S,D)
  float* pm    = (float*)(ws + 30u * 1048576);    //  4 MiB (L,S) f32
  short* E     = (short*)(ws + 34u * 1048576);    //  2 MiB (L,S) bf16
  float* pmmax = (float*)(ws + 36u * 1048576);    //  4 KiB
  float* pmsum = (float*)(ws + 36u * 1048576 + 4096);       // 4 KiB
  float* bandS = (float*)(ws + 37u * 1048576);    //  1 MiB (bh,l,8) f32
  short* out1  = (short*)(ws + 38u * 1048576);    //  4 MiB (B,L,512) bf16
  short* Sbf   = (short*)(ws + 42u * 1048576);    // 64 MiB (bh,L,S) bf16 -> 106 MiB

  const dim3 blk(256);

  // 0) cvt inputs + bandS init; weight transpose
  hipLaunchKernelGGL(cvt_inputs_kernel, dim3(3072), blk, 0, stream,
                     queries, keys, values, xbf, bandS);
  hipLaunchKernelGGL(wtrans_kernel, dim3(16, 16, 4), blk, 0, stream,
                     Wq, Wk, Wv, Wo, WT);

  // 1) q/k/v projections, one launch
  hipLaunchKernelGGL(proj_qkv_kernel, dim3(DMODEL / 64, (B_ * L_) / 64, 3),
                     blk, 0, stream, xbf, WT, qkbf, vT, vS);

  // 2) scores bf16 + exact band extraction
  hipLaunchKernelGGL(scores_bf16_kernel, dim3(S_ / 64, L_ / 64, NBH), blk, 0, stream,
                     qkbf, qkbf + 2097152, Sbf, bandS);

  // 3) path_mean (tiled gather over bf16 scores)
  hipLaunchKernelGGL(path_mean_kernel, dim3(1024), blk, 0, stream, Sbf, pm);

  // 4) pm stats + E
  hipLaunchKernelGGL(pm_stats_kernel, dim3(L_ / 4), blk, 0, stream,
                     pm, E, pmmax, pmsum);

  // 5) EV GEMM with fused attn write + band epilogue
  hipLaunchKernelGGL(ev_fused_kernel, dim3(L_ / 64, NBH), blk, 0, stream,
                     E, vT, vS, bandS, pmmax, pmsum, attn, out1);

  // 6) out = out1 @ W_o
  hipLaunchKernelGGL(proj_out_kernel, dim3(DMODEL / 64, (B_ * L_) / 64), blk, 0, stream,
                     out1, WT + 786432, out);
}